// Round 4
// baseline (2552.746 us; speedup 1.0000x reference)
//
#include <hip/hip_runtime.h>
#include <cstddef>

#define INPUT_D 100
#define HID 64
#define H4 256
#define BATCH 1024
#define SEQT 512
#define TC 8
#define NCHUNK (SEQT / TC)   // 64
#define BB 2                 // batch rows per block
#define NB (BATCH / BB)      // 512 blocks

__device__ __forceinline__ float sigm(float x) {
    return __builtin_amdgcn_rcpf(1.0f + __expf(-x));
}
__device__ __forceinline__ float tanh_f(float x) {
    // tanh(x) = 1 - 2/(exp(2x)+1); saturates correctly for |x| large
    float e = __expf(2.0f * x);
    return 1.0f - 2.0f * __builtin_amdgcn_rcpf(e + 1.0f);
}

__global__ __launch_bounds__(256, 2) void lstm2_fused(
    const float* __restrict__ x,
    const float* __restrict__ Wih0, const float* __restrict__ Whh0,
    const float* __restrict__ bih0, const float* __restrict__ bhh0,
    const float* __restrict__ Wih1, const float* __restrict__ Whh1,
    const float* __restrict__ bih1, const float* __restrict__ bhh1,
    const float* __restrict__ fcw, const float* __restrict__ fcb,
    float* __restrict__ y)
{
    __shared__ __align__(16) float xs[BB][TC * INPUT_D];   // 6.4 KB
    __shared__ float xg[TC][BB][H4];                       // 16 KB
    __shared__ __align__(16) float h0s[HID][BB];           // h of layer 0, [k][b]
    __shared__ __align__(16) float h1s[HID][BB];           // h of layer 1
    __shared__ float gbuf[4][BB][HID];                     // gate exchange
    __shared__ float ybuf[TC][BB];

    const int tid = threadIdx.x;
    const int u = tid & 63;
    const int r = tid;                 // gate-row in [0,256): g*64+u
    const int bbase = blockIdx.x * BB;

    // recurrent-path weights resident in registers (row r of each matrix)
    float whh0r[HID], wih1r[HID], whh1r[HID];
    #pragma unroll
    for (int k = 0; k < HID; k += 4) {
        *(float4*)(whh0r + k) = *(const float4*)(Whh0 + (size_t)r * HID + k);
        *(float4*)(wih1r + k) = *(const float4*)(Wih1 + (size_t)r * HID + k);
        *(float4*)(whh1r + k) = *(const float4*)(Whh1 + (size_t)r * HID + k);
    }
    const float bias0 = bih0[r] + bhh0[r];
    const float bias1 = bih1[r] + bhh1[r];
    const float fw = fcw[u];
    const float fb = fcb[0];

    float c0[BB], c1[BB];
    #pragma unroll
    for (int b = 0; b < BB; ++b) { c0[b] = 0.f; c1[b] = 0.f; }
    if (tid < HID) {
        #pragma unroll
        for (int b = 0; b < BB; ++b) { h0s[tid][b] = 0.f; h1s[tid][b] = 0.f; }
    }

    for (int ch = 0; ch < NCHUNK; ++ch) {
        const int t0 = ch * TC;

        // ---------- stage x chunk (coalesced) ----------
        #pragma unroll
        for (int b = 0; b < BB; ++b) {
            const float* xp = x + ((size_t)(bbase + b) * SEQT + t0) * INPUT_D;
            for (int i = tid; i < TC * INPUT_D; i += 256) xs[b][i] = xp[i];
        }
        __syncthreads();

        // ---------- phase A: xg[t][b][r] = bias0 + W_ih0[r,:] . x[b,t,:] ----------
        float acc[BB][TC];
        #pragma unroll
        for (int b = 0; b < BB; ++b)
            #pragma unroll
            for (int t = 0; t < TC; ++t) acc[b][t] = bias0;

        const float* wrow = Wih0 + (size_t)r * INPUT_D;
        #pragma unroll 5
        for (int kq = 0; kq < INPUT_D / 4; ++kq) {
            const float4 w = *(const float4*)(wrow + kq * 4);
            #pragma unroll
            for (int b = 0; b < BB; ++b)
                #pragma unroll
                for (int t = 0; t < TC; ++t) {
                    const float4 xv = *(const float4*)(&xs[b][t * INPUT_D + kq * 4]);
                    float a = acc[b][t];
                    a = fmaf(w.x, xv.x, a);
                    a = fmaf(w.y, xv.y, a);
                    a = fmaf(w.z, xv.z, a);
                    a = fmaf(w.w, xv.w, a);
                    acc[b][t] = a;
                }
        }
        #pragma unroll
        for (int b = 0; b < BB; ++b)
            #pragma unroll
            for (int t = 0; t < TC; ++t) xg[t][b][r] = acc[b][t];
        __syncthreads();

        // ---------- phase B: TC recurrent steps ----------
        for (int tc = 0; tc < TC; ++tc) {
            // ---- layer 0 gate pre-activations ----
            float a0[BB];
            #pragma unroll
            for (int b = 0; b < BB; ++b) a0[b] = xg[tc][b][r];
            #pragma unroll
            for (int k = 0; k < HID; k += 2) {
                const float4 h = *(const float4*)(&h0s[k][0]);  // h0[k][0..1], h0[k+1][0..1]
                a0[0] = fmaf(whh0r[k],     h.x, a0[0]);
                a0[1] = fmaf(whh0r[k],     h.y, a0[1]);
                a0[0] = fmaf(whh0r[k + 1], h.z, a0[0]);
                a0[1] = fmaf(whh0r[k + 1], h.w, a0[1]);
            }
            {
                const int g = tid >> 6;
                #pragma unroll
                for (int b = 0; b < BB; ++b) gbuf[g][b][u] = a0[b];
            }
            __syncthreads();

            if (tid < HID) {
                float hv[BB];
                #pragma unroll
                for (int b = 0; b < BB; ++b) {
                    const float gi = gbuf[0][b][u];
                    const float gf = gbuf[1][b][u];
                    const float gg = gbuf[2][b][u];
                    const float go = gbuf[3][b][u];
                    const float iv = sigm(gi), fv = sigm(gf);
                    const float cv = tanh_f(gg), ov = sigm(go);
                    c0[b] = fmaf(fv, c0[b], iv * cv);
                    hv[b] = ov * tanh_f(c0[b]);
                }
                *(float2*)(&h0s[u][0]) = make_float2(hv[0], hv[1]);
            }
            __syncthreads();

            // ---- layer 1 gate pre-activations ----
            float a1[BB];
            #pragma unroll
            for (int b = 0; b < BB; ++b) a1[b] = bias1;
            #pragma unroll
            for (int k = 0; k < HID; k += 2) {
                const float4 hx = *(const float4*)(&h0s[k][0]);
                const float4 hp = *(const float4*)(&h1s[k][0]);
                a1[0] = fmaf(wih1r[k],     hx.x, a1[0]);
                a1[1] = fmaf(wih1r[k],     hx.y, a1[1]);
                a1[0] = fmaf(wih1r[k + 1], hx.z, a1[0]);
                a1[1] = fmaf(wih1r[k + 1], hx.w, a1[1]);
                a1[0] = fmaf(whh1r[k],     hp.x, a1[0]);
                a1[1] = fmaf(whh1r[k],     hp.y, a1[1]);
                a1[0] = fmaf(whh1r[k + 1], hp.z, a1[0]);
                a1[1] = fmaf(whh1r[k + 1], hp.w, a1[1]);
            }
            {
                const int g = tid >> 6;
                #pragma unroll
                for (int b = 0; b < BB; ++b) gbuf[g][b][u] = a1[b];
            }
            __syncthreads();

            if (tid < HID) {
                float hv[BB], p[BB];
                #pragma unroll
                for (int b = 0; b < BB; ++b) {
                    const float gi = gbuf[0][b][u];
                    const float gf = gbuf[1][b][u];
                    const float gg = gbuf[2][b][u];
                    const float go = gbuf[3][b][u];
                    const float iv = sigm(gi), fv = sigm(gf);
                    const float cv = tanh_f(gg), ov = sigm(go);
                    c1[b] = fmaf(fv, c1[b], iv * cv);
                    hv[b] = ov * tanh_f(c1[b]);
                    p[b] = fw * hv[b];
                }
                *(float2*)(&h1s[u][0]) = make_float2(hv[0], hv[1]);
                // FC reduction over 64 units
                #pragma unroll
                for (int off = 32; off >= 1; off >>= 1) {
                    #pragma unroll
                    for (int b = 0; b < BB; ++b) p[b] += __shfl_xor(p[b], off, 64);
                }
                if (u == 0) {
                    #pragma unroll
                    for (int b = 0; b < BB; ++b) ybuf[tc][b] = p[b] + fb;
                }
            }
            __syncthreads();
        }

        // ---------- store y chunk ----------
        if (tid < TC * BB) {
            const int b = tid / TC;
            const int t = tid % TC;
            y[(size_t)(bbase + b) * SEQT + t0 + t] = ybuf[t][b];
        }
        // safe: next chunk's first LDS writes (xs) don't alias ybuf; ybuf is
        // next written only after the phase-A barrier of chunk ch+1.
    }
}

extern "C" void kernel_launch(void* const* d_in, const int* in_sizes, int n_in,
                              void* d_out, int out_size, void* d_ws, size_t ws_size,
                              hipStream_t stream) {
    const float* x    = (const float*)d_in[0];
    const float* Wih0 = (const float*)d_in[1];
    const float* Whh0 = (const float*)d_in[2];
    const float* bih0 = (const float*)d_in[3];
    const float* bhh0 = (const float*)d_in[4];
    const float* Wih1 = (const float*)d_in[5];
    const float* Whh1 = (const float*)d_in[6];
    const float* bih1 = (const float*)d_in[7];
    const float* bhh1 = (const float*)d_in[8];
    const float* fcw  = (const float*)d_in[9];
    const float* fcb  = (const float*)d_in[10];
    float* y = (float*)d_out;

    lstm2_fused<<<NB, 256, 0, stream>>>(x, Wih0, Whh0, bih0, bhh0,
                                        Wih1, Whh1, bih1, bhh1, fcw, fcb, y);
}